// Round 13
// baseline (113.829 us; speedup 1.0000x reference)
//
#include <hip/hip_runtime.h>
#include <hip/hip_bf16.h>

// ---------------- problem constants ----------------
#define BATCH   16
#define C_INF   4
#define H_IN    128
#define W_IN    128
#define HID     50
#define F_OUT   18
#define HO      120
#define WO      120
#define OH      122
#define OW      122
#define NPOS    (BATCH * HO * WO)       // 230400 = 1800 * 128
#define MBLK    128                     // positions per block (4 waves x 32 rows)
#define NBLKS   (NPOS / MBLK)           // 1800 (divisible by 8 -> clean XCD swizzle)
#define NXCD    8

// frag-packed weight blob sizes (fp16 shorts, SINGLE precision - no hi/lo)
#define NB1     (11*4*64*8)             // 22528 shorts = 44 frags
#define NB2     (2*4*64*8)              // 4096
#define NB3     (2*2*64*8)              // 2048
#define NWF     (NB1 + NB2 + NB3)       // 28672
#define WOFF    (NPOS * F_OUT)          // out3 elements (fp16 shorts)
#define NXC     (BATCH * C_INF * H_IN * W_IN)   // 1048576
#define PREP_BLOCKS  ((NWF + 255) / 256)        // 112
#define XCONV_BLOCKS (NXC / (256 * 8))          // 512
#define CW      16                      // fold: 8-wide chunks per row (16*8 >= 122)
#define NSTG    (36*512)                // staged L1 frags: 36 x 1KiB = 18432 shorts

typedef float    v4f     __attribute__((ext_vector_type(4)));
typedef short    short4v __attribute__((ext_vector_type(4)));
typedef short    short8  __attribute__((ext_vector_type(8)));
typedef _Float16 v8hf    __attribute__((ext_vector_type(8)));
typedef int      v4i     __attribute__((ext_vector_type(4)));
typedef short8 short8_a4 __attribute__((aligned(4)));   // 16B load, 4B-aligned

__device__ inline short f2h(float x) {
    _Float16 h = (_Float16)x;                    // RNE, 11 mantissa bits
    return __builtin_bit_cast(short, h);
}
__device__ inline float h2f(short s) {
    return (float)__builtin_bit_cast(_Float16, s);
}

// asm 16B global load: issues WHERE PLACED, output register is FORCED distinct,
// compiler cannot serialize/split it. Result is valid only after s_waitcnt
// vmcnt(0) (we only ever use full drains -> no counting hazards with
// compiler-emitted loads mixed into the window).
__device__ inline v4i aload16(const void* p) {
    v4i r;
    asm volatile("global_load_dwordx4 %0, %1, off" : "=v"(r) : "v"(p));
    return r;
}
__device__ inline void vm_drain() {
    asm volatile("s_waitcnt vmcnt(0)" ::: "memory");
    __builtin_amdgcn_sched_barrier(0);   // rule #18: block hoisting past the wait
}

// swizzled h-LDS index (stride 64 shorts = 128B rows; XOR row-bits into the
// 16B-chunk bits to break the 16-way bank conflict of the stride-128B layout)
__device__ inline int hswz(int m, int j) {
    return (m * 64 + j) ^ ((m & 7) << 3);
}

// slot -> k bijection for layer 1 (contiguous kj in the low 9 k-steps)
__device__ inline int slot_to_k1(int s, int qb, int e) {
    if (s < 9) {
        int pair = s*4 + qb;            // (c,ki) in [0,36)
        int c = pair/9, ki = pair - c*9;
        return c*81 + ki*9 + e;         // kj = e in [0,8)
    }
    int r = (s-9)*32 + qb*8 + e;        // remainder: kj = 8
    if (r >= 36) return -1;
    int c = r/9, ki = r - c*9;
    return c*81 + ki*9 + 8;
}

// ---------------- prep: weights + x -> fp16 (parity pair) ----------------
__global__ __launch_bounds__(256)
void prep_kernel(const float* __restrict__ x,
                 const float* __restrict__ W1, const float* __restrict__ W2,
                 const float* __restrict__ W3, short* __restrict__ wf,
                 short* __restrict__ xe, short* __restrict__ xo)
{
    const int blk = blockIdx.x;
    if (blk >= PREP_BLOCKS) {
        // x -> fp16: xe[i] = h(x[i]); xo[i] = h(x[i+1])  (aligned stores)
        const int j = ((blk - PREP_BLOCKS)*256 + (int)threadIdx.x) * 8;
        v4f a = *(const v4f*)&x[j];
        v4f b = *(const v4f*)&x[j + 4];
        float c9 = (j + 8 < NXC) ? x[j + 8] : 0.f;
        short s[9];
        #pragma unroll
        for (int e = 0; e < 4; ++e) { s[e] = f2h(a[e]); s[e+4] = f2h(b[e]); }
        s[8] = f2h(c9);
        short8 ve, vo;
        #pragma unroll
        for (int e = 0; e < 8; ++e) { ve[e] = s[e]; vo[e] = s[e+1]; }
        *(short8*)&xe[j] = ve;
        *(short8*)&xo[j] = vo;
        return;
    }
    int i = blk * 256 + threadIdx.x;
    if (i >= NWF) return;
    float val;
    if (i < NB1) {
        int t = i;
        int e = t & 7, lane = (t >> 3) & 63;
        int rest = t >> 9;                   // s*4 + u
        int u = rest & 3, s = rest >> 2;
        int k = slot_to_k1(s, lane >> 4, e);
        int n = u*16 + (lane & 15);
        val = (k >= 0 && n < HID) ? W1[k*HID + n] : 0.f;
    } else if (i < NB1 + NB2) {
        int t = i - NB1;
        int e = t & 7, lane = (t >> 3) & 63;
        int rest = t >> 9;
        int u = rest & 3, s = rest >> 2;
        int k = s*32 + ((lane >> 4) << 3) + e;   // linear (LDS h layout)
        int n = u*16 + (lane & 15);
        val = (k < HID && n < HID) ? W2[k*HID + n] : 0.f;
    } else {
        int t = i - NB1 - NB2;
        int e = t & 7, lane = (t >> 3) & 63;
        int rest = t >> 9;
        int u = rest & 1, s = rest >> 1;
        int k = s*32 + ((lane >> 4) << 3) + e;
        int n = u*16 + (lane & 15);
        val = (k < HID && n < F_OUT) ? W3[k*F_OUT + n] : 0.f;
    }
    wf[i] = f2h(val);
}

// ---------------- fused 3-layer MLP (asm-batched VMEM) ----------------
// 13 rounds at VGPR 56-84 = the compiler ALWAYS serializes the VMEM stream
// (load-wait-use-reuse), ~72 x ~400cy = the whole 14us block lifetime. This
// version forces true batching with inline-asm global_load_dwordx4: 18 A-frag
// loads issued back-to-back in the prologue (drained free by the staging
// barrier's vmcnt(0)); B1-remainder and B2/B3 as asm batches + single
// vm_drain each. Only vmcnt(0) waits -> no counting hazards. L1 main loop is
// pure ds_read+MFMA. Forced live ~156 VGPR < 170 cap at (256,3); LDS 53248B
// -> 3 blocks/CU.
__global__ __launch_bounds__(256, 3)
void mfma_mlp(const short* __restrict__ xe, const short* __restrict__ xo,
              const float* __restrict__ b1, const float* __restrict__ b2,
              const float* __restrict__ b3,
              const short* __restrict__ wf, short* __restrict__ out3)
{
    __shared__ short wlds[NSTG];       // 36864 B: B1 frags 0..35
    __shared__ short h_lds[128 * 64];  // 16384 B; wave w owns rows [w*32, w*32+32)

    const int tid  = threadIdx.x;
    const int lane = tid & 63;
    const int w    = tid >> 6;
    const int q    = lane >> 4, col = lane & 15;
    // XCD-aware swizzle (1800 = 8 * 225, exact bijection)
    const int swz   = (blockIdx.x & 7) * (NBLKS / NXCD) + (blockIdx.x >> 3);
    const int mbase = swz * MBLK;
    const int mw    = w * 32;          // this wave's row base within the block

    // per-row x pointer, parity-selected so 16B a-loads are 4B-aligned
    const short* xp[2];
    #pragma unroll
    for (int t = 0; t < 2; ++t) {
        int pos = mbase + mw + t*16 + col;
        int b   = pos / (HO*WO); int rem = pos - b*(HO*WO);
        int y   = rem / WO;      int xc  = rem - y*WO;
        int bi  = b*(C_INF*H_IN*W_IN) + y*W_IN + xc;
        xp[t] = (bi & 1) ? (xo + (bi - 1)) : (xe + bi);
    }

    // ---- asm-issue ALL 18 main-step A loads (oldest in queue, batched) ----
    v4i ahm[9][2];
    #pragma unroll
    for (int s = 0; s < 9; ++s) {
        const int pair = s*4 + q;
        const int c = pair/9, ki = pair - c*9;
        const int off = c*(H_IN*W_IN) + ki*W_IN;
        #pragma unroll
        for (int t = 0; t < 2; ++t)
            ahm[s][t] = aload16(xp[t] + off);
    }

    // ---- stage B1 frags 0..35 into LDS (9 x 4KiB chunks, 16B per lane) ----
    #pragma unroll
    for (int it = 0; it < 9; ++it) {
        const int cbase = it*256 + w*64;         // wave-uniform 16B-chunk base
        const short* g  = wf + (cbase + lane)*8; // per-lane global source
        __builtin_amdgcn_global_load_lds(
            (const __attribute__((address_space(1))) void*)g,
            (__attribute__((address_space(3))) void*)&wlds[cbase*8],
            16, 0, 0);
    }

    // remainder A gather (kj=8): compiler scalar loads, drained by the barrier
    short8 ahr[2][2];
    #pragma unroll
    for (int sr = 0; sr < 2; ++sr) {
        #pragma unroll
        for (int e = 0; e < 8; ++e) {
            int r = sr*32 + q*8 + e;
            bool valid = (r < 36);
            int c = valid ? r/9 : 0;
            int ki = r - c*9;
            int off = c*(H_IN*W_IN) + ki*W_IN + 8;
            #pragma unroll
            for (int t = 0; t < 2; ++t)
                ahr[sr][t][e] = valid ? xp[t][off] : (short)0;
        }
    }

    // hoisted bias loads (overlap the in-flight batch)
    float bias1[4], bias2[4], bias3[2];
    #pragma unroll
    for (int u = 0; u < 4; ++u) {
        int j = u*16 + col;
        bias1[u] = (j < HID) ? b1[j] : 0.f;
        bias2[u] = (j < HID) ? b2[j] : 0.f;
    }
    #pragma unroll
    for (int u = 0; u < 2; ++u) {
        int j = u*16 + col;
        bias3[u] = (j < F_OUT) ? b3[j] : 0.f;
    }

    const v4i* B1L = (const v4i*)wf + lane;
    const v4i* B2L = (const v4i*)(wf + NB1) + lane;
    const v4i* B3L = (const v4i*)(wf + NB1 + NB2) + lane;

    __syncthreads();                   // emits vmcnt(0): batch + DMA all landed
    __builtin_amdgcn_sched_barrier(0); // nothing crosses the drain point

    // ---------------- layer 1: K=324 (11 k-steps), N=64 ----------------
    v4f acc[2][4];
    #pragma unroll
    for (int t = 0; t < 2; ++t)
        #pragma unroll
        for (int u = 0; u < 4; ++u)
            acc[t][u] = (v4f){0.f, 0.f, 0.f, 0.f};

    // 9 steps: B from LDS (conflict-free ds_read_b128), A already in regs
    #pragma unroll
    for (int s = 0; s < 9; ++s) {
        #pragma unroll
        for (int u = 0; u < 4; ++u) {
            v4i bv = *(const v4i*)&wlds[((s*4 + u)*64 + lane)*8];
            v8hf bh = __builtin_bit_cast(v8hf, bv);
            #pragma unroll
            for (int t = 0; t < 2; ++t) {
                v8hf a_h = __builtin_bit_cast(v8hf, ahm[s][t]);
                acc[t][u] = __builtin_amdgcn_mfma_f32_16x16x32_f16(a_h, bh, acc[t][u], 0, 0, 0);
            }
        }
    }

    // ---- B1 remainder frags 36..43: asm batch + one drain ----
    v4i brem[8];
    #pragma unroll
    for (int i = 0; i < 8; ++i) brem[i] = aload16(B1L + (36 + i)*64);
    vm_drain();

    #pragma unroll
    for (int sr = 0; sr < 2; ++sr) {
        #pragma unroll
        for (int u = 0; u < 4; ++u) {
            v8hf bh = __builtin_bit_cast(v8hf, brem[sr*4 + u]);
            #pragma unroll
            for (int t = 0; t < 2; ++t) {
                v8hf a_h = __builtin_bit_cast(v8hf, ahr[sr][t]);
                acc[t][u] = __builtin_amdgcn_mfma_f32_16x16x32_f16(a_h, bh, acc[t][u], 0, 0, 0);
            }
        }
    }

    // ---- B2/B3: asm batch issued NOW; L1 epilogue hides the latency ----
    v4i b2r[8], b3r[4];
    #pragma unroll
    for (int i = 0; i < 8; ++i) b2r[i] = aload16(B2L + i*64);
    #pragma unroll
    for (int i = 0; i < 4; ++i) b3r[i] = aload16(B3L + i*64);

    // epilogue L1: + b1, relu, fp16 into this wave's LDS rows (no barrier needed)
    #pragma unroll
    for (int u = 0; u < 4; ++u) {
        #pragma unroll
        for (int t = 0; t < 2; ++t) {
            #pragma unroll
            for (int r = 0; r < 4; ++r) {
                float v = fmaxf(acc[t][u][r] + bias1[u], 0.f);
                int m = mw + t*16 + q*4 + r;
                h_lds[hswz(m, u*16 + col)] = f2h(v);
            }
        }
    }

    vm_drain();                        // b2r/b3r resident

    // ---------------- layer 2: K=50 (2 k-steps), N=64 ----------------
    v4f acc2[2][4];
    #pragma unroll
    for (int t = 0; t < 2; ++t)
        #pragma unroll
        for (int u = 0; u < 4; ++u)
            acc2[t][u] = (v4f){0.f, 0.f, 0.f, 0.f};

    #pragma unroll
    for (int s = 0; s < 2; ++s) {
        short8 ah2[2];
        #pragma unroll
        for (int t = 0; t < 2; ++t) {
            int m = mw + t*16 + col;
            ah2[t] = *(const short8*)&h_lds[hswz(m, s*32 + q*8)];
        }
        #pragma unroll
        for (int u = 0; u < 4; ++u) {
            v8hf bh = __builtin_bit_cast(v8hf, b2r[s*4 + u]);
            #pragma unroll
            for (int t = 0; t < 2; ++t) {
                v8hf a_h = __builtin_bit_cast(v8hf, ah2[t]);
                acc2[t][u] = __builtin_amdgcn_mfma_f32_16x16x32_f16(a_h, bh, acc2[t][u], 0, 0, 0);
            }
        }
    }

    // epilogue L2 (within-wave DS is FIFO)
    #pragma unroll
    for (int u = 0; u < 4; ++u) {
        #pragma unroll
        for (int t = 0; t < 2; ++t) {
            #pragma unroll
            for (int r = 0; r < 4; ++r) {
                float v = fmaxf(acc2[t][u][r] + bias2[u], 0.f);
                int m = mw + t*16 + q*4 + r;
                h_lds[hswz(m, u*16 + col)] = f2h(v);
            }
        }
    }

    // ---------------- layer 3: K=50 (2 k-steps), N=18 (pad 32) ----------------
    v4f acc3[2][2];
    #pragma unroll
    for (int t = 0; t < 2; ++t)
        #pragma unroll
        for (int u = 0; u < 2; ++u)
            acc3[t][u] = (v4f){0.f, 0.f, 0.f, 0.f};

    #pragma unroll
    for (int s = 0; s < 2; ++s) {
        short8 ah3[2];
        #pragma unroll
        for (int t = 0; t < 2; ++t) {
            int m = mw + t*16 + col;
            ah3[t] = *(const short8*)&h_lds[hswz(m, s*32 + q*8)];
        }
        #pragma unroll
        for (int u = 0; u < 2; ++u) {
            v8hf bh = __builtin_bit_cast(v8hf, b3r[s*2 + u]);
            #pragma unroll
            for (int t = 0; t < 2; ++t) {
                v8hf a_h = __builtin_bit_cast(v8hf, ah3[t]);
                acc3[t][u] = __builtin_amdgcn_mfma_f32_16x16x32_f16(a_h, bh, acc3[t][u], 0, 0, 0);
            }
        }
    }

    // epilogue: + b3, fp16-pack, planar 8-B non-temporal stores
    #pragma unroll
    for (int u = 0; u < 2; ++u) {
        int j = u*16 + col;
        if (j < F_OUT) {
            #pragma unroll
            for (int t = 0; t < 2; ++t) {
                short4v vs;
                #pragma unroll
                for (int r = 0; r < 4; ++r) vs[r] = f2h(acc3[t][u][r] + bias3[u]);
                __builtin_nontemporal_store(vs,
                    (short4v*)&out3[j*NPOS + mbase + mw + t*16 + q*4]);
            }
        }
    }
}

// ---------------- fold (overlap-add) + divide, 8-wide vectorized ----------------
__global__ __launch_bounds__(256)
void fold_kernel(const short* __restrict__ out3, float* __restrict__ out)
{
    const int idx = blockIdx.x * 256 + threadIdx.x;
    const int total = BATCH * 2 * OH * CW;
    if (idx >= total) return;

    int t = idx;
    const int cx = t % CW; t /= CW;
    const int oy = t % OH; t /= OH;
    const int c  = t & 1;  t >>= 1;
    const int b  = t;
    const int ox0 = cx * 8;

    // interior fast path: full 3x3 windows for all 8 pixels, aligned loads
    if (oy >= 2 && oy < HO && cx >= 1 && cx <= 14) {
        float accv[8];
        #pragma unroll
        for (int e = 0; e < 8; ++e) accv[e] = 0.f;
        #pragma unroll
        for (int ki = 0; ki < 3; ++ki) {
            const int y    = oy - ki;
            const int rowb = (b*HO + y)*WO;
            const int ob   = (c*3 + ki)*3;
            short8 v0 = *(const short8_a4*)&out3[(ob + 0)*NPOS + rowb + ox0];
            short8 v1 = *(const short8_a4*)&out3[(ob + 1)*NPOS + rowb + ox0 - 2];
            int   v1b = *(const int*)      &out3[(ob + 1)*NPOS + rowb + ox0 + 6];
            short8 v2 = *(const short8_a4*)&out3[(ob + 2)*NPOS + rowb + ox0 - 2];
            #pragma unroll
            for (int e = 0; e < 8; ++e) {
                accv[e] += h2f(v0[e]);
                accv[e] += (e < 7) ? h2f(v1[e + 1]) : h2f((short)(v1b & 0xffff));
                accv[e] += h2f(v2[e]);
            }
        }
        float* op = &out[((b*2 + c)*OH + oy)*OW + ox0];
        #pragma unroll
        for (int e = 0; e < 8; ++e) op[e] = accv[e] / 9.f;
        return;
    }

    // boundary: per-pixel clamped windows (guard instead of break: uniform unroll)
    #pragma unroll
    for (int e = 0; e < 8; ++e) {
        const int ox = ox0 + e;
        if (ox < OW) {
            const int ylo = max(0, oy - 2), yhi = min(HO - 1, oy);
            const int xlo = max(0, ox - 2), xhi = min(WO - 1, ox);
            float s = 0.f;
            for (int y = ylo; y <= yhi; ++y) {
                const int ki = oy - y;
                for (int xx = xlo; xx <= xhi; ++xx) {
                    const int kj = ox - xx;
                    const int o  = (c*3 + ki)*3 + kj;
                    s += h2f(out3[o*NPOS + (b*HO + y)*WO + xx]);
                }
            }
            const float div = (float)((yhi - ylo + 1) * (xhi - xlo + 1));
            out[((b*2 + c)*OH + oy)*OW + ox] = s / div;
        }
    }
}

// ---------------- launch ----------------
extern "C" void kernel_launch(void* const* d_in, const int* in_sizes, int n_in,
                              void* d_out, int out_size, void* d_ws, size_t ws_size,
                              hipStream_t stream)
{
    const float* x  = (const float*)d_in[0];
    const float* W1 = (const float*)d_in[1];
    const float* b1 = (const float*)d_in[2];
    const float* W2 = (const float*)d_in[3];
    const float* b2 = (const float*)d_in[4];
    const float* W3 = (const float*)d_in[5];
    const float* b3 = (const float*)d_in[6];

    short* out3 = (short*)d_ws;                               // 8.29 MB (fp16)
    short* wf   = out3 + WOFF;                                // 56 KB (16B-aligned)
    short* xe   = wf + NWF;                                   // 2.0 MB
    short* xo   = xe + NXC;                                   // 2.0 MB (shifted copy)

    prep_kernel<<<PREP_BLOCKS + XCONV_BLOCKS, 256, 0, stream>>>(x, W1, W2, W3, wf, xe, xo);

    mfma_mlp<<<NBLKS, 256, 0, stream>>>(xe, xo, b1, b2, b3, wf, out3);

    const int total = BATCH * 2 * OH * CW;
    fold_kernel<<<(total + 255) / 256, 256, 0, stream>>>(out3, (float*)d_out);
}